// Round 1
// baseline (266.326 us; speedup 1.0000x reference)
//
#include <hip/hip_runtime.h>
#include <hip/hip_bf16.h>
#include <stdint.h>

#define SS 8192
#define DD 1024
#define RR 16
#define OO 512

typedef __bf16 bf16_8 __attribute__((ext_vector_type(8)));
typedef __bf16 bf16_4 __attribute__((ext_vector_type(4)));
typedef float f32_4 __attribute__((ext_vector_type(4)));

typedef __attribute__((address_space(1))) void g1_void;
typedef __attribute__((address_space(3))) void lds_void;

__device__ __forceinline__ void gload_lds16(const void* g, void* l) {
  // CK-style addrspace plumbing: global generic ptr == flat addr; LDS generic
  // ptr truncates to the 32-bit AS(3) offset. HW writes lane i at lds+16*i.
  __builtin_amdgcn_global_load_lds((g1_void*)(uintptr_t)g,
                                   (lds_void*)(uint32_t)(uintptr_t)l, 16, 0, 0);
}

__device__ __forceinline__ float fast_sigmoid(float x) {
  return __builtin_amdgcn_rcpf(1.0f + __expf(-x));
}

__global__ void somfnn_cvt(const float* __restrict__ src, __bf16* __restrict__ dst, int n4) {
  int i = blockIdx.x * blockDim.x + threadIdx.x;
  if (i >= n4) return;
  float4 v = ((const float4*)src)[i];
  bf16_4 o;
  o[0] = (__bf16)v.x; o[1] = (__bf16)v.y; o[2] = (__bf16)v.z; o[3] = (__bf16)v.w;
  ((bf16_4*)dst)[i] = o;
}

// Fused GEMM + sigmoid + rule-reduce.
// Tile: BM=128 rows (s) x BN=128 cols (o), iterating 8 rules per block.
// LDS chunks: 16B = 8 consecutive k of one row; chunk(row,k8) = row*8 + (k8 ^ (row&7))
// (XOR swizzle -> conflict-free ds_read_b128 AND contiguous lane-order fill
//  compatible with global_load_lds's uniform-base + lane*16 semantics).
template <bool PRECONV>
__global__ __launch_bounds__(256, 2) void somfnn_gemm(
    const void* __restrict__ Xp, const void* __restrict__ Wp,
    const float* __restrict__ bias_g, const float* __restrict__ lam_g,
    float* __restrict__ out) {
  constexpr int BM = 128, BN = 128, BK = 64;
  constexpr int TILE = BM * BK;          // 8192 bf16 = 16KB
  constexpr int NSTEP = 8 * (DD / BK);   // 8 rules * 16 k-tiles = 128

  __shared__ __align__(16) __bf16 lds_a[2][TILE];
  __shared__ __align__(16) __bf16 lds_b[2][TILE];
  __shared__ float lds_bias[8 * BN];
  __shared__ float lds_lam[8 * BM];

  const int tid = threadIdx.x;
  const int l = tid & 63;
  const int w = tid >> 6;
  const int lane15 = l & 15;
  const int q = l >> 4;
  const int wm = w >> 1;   // 2x2 wave grid, each wave 64x64
  const int wn = w & 1;

  const int bid = blockIdx.x;
  const int rhalf = bid & 1;          // XCD swizzle: (rhalf, ob) const per XCD
  const int ob = (bid >> 1) & 3;
  const int sb = bid >> 3;
  const int s0 = sb * BM;
  const int o0 = ob * BN;
  const int r0 = rhalf * 8;

  // preload bias + lambda slices for this block's 8 rules
  for (int idx = tid; idx < 8 * BN; idx += 256) {
    int rr = idx >> 7, j = idx & 127;
    lds_bias[idx] = bias_g[(r0 + rr) * OO + o0 + j];
  }
  for (int idx = tid; idx < 8 * BM; idx += 256) {
    int rr = idx >> 7, i = idx & 127;
    lds_lam[idx] = lam_g[(s0 + i) * RR + (r0 + rr)];
  }

  // staging descriptors: 4 chunks per thread per matrix per step
  int goffs[4];  // global elem offset within tile: row*DD + k8*8
  int coffs[4];  // lds elem offset: chunk*8 (fallback ds_write path)
#pragma unroll
  for (int i = 0; i < 4; ++i) {
    int c = (w * 4 + i) * 64 + l;
    int row = c >> 3;
    int k8 = (c & 7) ^ (row & 7);
    goffs[i] = row * DD + k8 * 8;
    coffs[i] = c * 8;
  }

  // fragment LDS elem offsets for ks=0; ks=1 is ^32 (chunk ^4)
  int afo[4], bfo[4];
#pragma unroll
  for (int t = 0; t < 4; ++t) {
    int ra = wm * 64 + t * 16 + lane15;
    afo[t] = (ra * 8 + (q ^ (ra & 7))) * 8;
    int rb = wn * 64 + t * 16 + lane15;
    bfo[t] = (rb * 8 + (q ^ (rb & 7))) * 8;
  }

  const __bf16* Xb = (const __bf16*)Xp;
  const __bf16* Wb = (const __bf16*)Wp;
  const float* Xf = (const float*)Xp;
  const float* Wf = (const float*)Wp;

  auto issue_pre = [&](int step, int buf) {
    int rl = step >> 4, kt = step & 15;
    const __bf16* ga = Xb + s0 * DD + kt * BK;
    const __bf16* gb = Wb + ((r0 + rl) * OO + o0) * DD + kt * BK;
#pragma unroll
    for (int i = 0; i < 4; ++i)
      gload_lds16(ga + goffs[i], &lds_a[buf][(w * 4 + i) * 512]);
#pragma unroll
    for (int i = 0; i < 4; ++i)
      gload_lds16(gb + goffs[i], &lds_b[buf][(w * 4 + i) * 512]);
  };

  float4 ra_[4][2], rb_[4][2];
  auto issue_fb = [&](int step) {
    int rl = step >> 4, kt = step & 15;
    const float* ga = Xf + s0 * DD + kt * BK;
    const float* gb = Wf + ((r0 + rl) * OO + o0) * DD + kt * BK;
#pragma unroll
    for (int i = 0; i < 4; ++i) {
      const float4* p = (const float4*)(ga + goffs[i]);
      ra_[i][0] = p[0];
      ra_[i][1] = p[1];
      const float4* pb = (const float4*)(gb + goffs[i]);
      rb_[i][0] = pb[0];
      rb_[i][1] = pb[1];
    }
  };
  auto commit_fb = [&](int buf) {
#pragma unroll
    for (int i = 0; i < 4; ++i) {
      bf16_8 t;
      t[0] = (__bf16)ra_[i][0].x; t[1] = (__bf16)ra_[i][0].y;
      t[2] = (__bf16)ra_[i][0].z; t[3] = (__bf16)ra_[i][0].w;
      t[4] = (__bf16)ra_[i][1].x; t[5] = (__bf16)ra_[i][1].y;
      t[6] = (__bf16)ra_[i][1].z; t[7] = (__bf16)ra_[i][1].w;
      *(bf16_8*)&lds_a[buf][coffs[i]] = t;
      bf16_8 u;
      u[0] = (__bf16)rb_[i][0].x; u[1] = (__bf16)rb_[i][0].y;
      u[2] = (__bf16)rb_[i][0].z; u[3] = (__bf16)rb_[i][0].w;
      u[4] = (__bf16)rb_[i][1].x; u[5] = (__bf16)rb_[i][1].y;
      u[6] = (__bf16)rb_[i][1].z; u[7] = (__bf16)rb_[i][1].w;
      *(bf16_8*)&lds_b[buf][coffs[i]] = u;
    }
  };

  f32_4 acc[4][4], oacc[4][4];
#pragma unroll
  for (int mi = 0; mi < 4; ++mi)
#pragma unroll
    for (int ni = 0; ni < 4; ++ni) {
      acc[mi][ni] = f32_4{0.f, 0.f, 0.f, 0.f};
      oacc[mi][ni] = f32_4{0.f, 0.f, 0.f, 0.f};
    }

  if constexpr (PRECONV) {
    issue_pre(0, 0);
  } else {
    issue_fb(0);
    commit_fb(0);
  }
  __syncthreads();

  for (int step = 0; step < NSTEP; ++step) {
    const int cur = step & 1;
    const bool more = (step + 1) < NSTEP;
    if (more) {
      if constexpr (PRECONV) issue_pre(step + 1, cur ^ 1);  // async into other buf
      else issue_fb(step + 1);
    }

    const __bf16* A = lds_a[cur];
    const __bf16* B = lds_b[cur];
#pragma unroll
    for (int ks = 0; ks < 2; ++ks) {
      const int xr = ks ? 32 : 0;
      bf16_8 av[4], bv[4];
#pragma unroll
      for (int mi = 0; mi < 4; ++mi) av[mi] = *(const bf16_8*)(A + (afo[mi] ^ xr));
#pragma unroll
      for (int ni = 0; ni < 4; ++ni) bv[ni] = *(const bf16_8*)(B + (bfo[ni] ^ xr));
#pragma unroll
      for (int mi = 0; mi < 4; ++mi)
#pragma unroll
        for (int ni = 0; ni < 4; ++ni)
          acc[mi][ni] =
              __builtin_amdgcn_mfma_f32_16x16x32_bf16(av[mi], bv[ni], acc[mi][ni], 0, 0, 0);
    }

    if constexpr (!PRECONV) {
      if (more) commit_fb(cur ^ 1);
    }

    if ((step & 15) == 15) {  // finished K for rule rl: fused epilogue
      const int rl = step >> 4;
      float lamv[4][4];
#pragma unroll
      for (int mi = 0; mi < 4; ++mi)
#pragma unroll
        for (int v = 0; v < 4; ++v)
          lamv[mi][v] = lds_lam[rl * BM + wm * 64 + mi * 16 + q * 4 + v];
#pragma unroll
      for (int ni = 0; ni < 4; ++ni) {
        const float bb = lds_bias[rl * BN + wn * 64 + ni * 16 + lane15];
#pragma unroll
        for (int mi = 0; mi < 4; ++mi)
#pragma unroll
          for (int v = 0; v < 4; ++v) {
            float h = fast_sigmoid(acc[mi][ni][v] + bb);
            oacc[mi][ni][v] += lamv[mi][v] * h;
            acc[mi][ni][v] = 0.f;
          }
      }
    }
    __syncthreads();
  }

  // combine the two rule-halves
#pragma unroll
  for (int mi = 0; mi < 4; ++mi)
#pragma unroll
    for (int ni = 0; ni < 4; ++ni)
#pragma unroll
      for (int v = 0; v < 4; ++v) {
        int row = s0 + wm * 64 + mi * 16 + q * 4 + v;
        int col = o0 + wn * 64 + ni * 16 + lane15;
        atomicAdd(&out[row * OO + col], oacc[mi][ni][v]);
      }
}

extern "C" void kernel_launch(void* const* d_in, const int* in_sizes, int n_in,
                              void* d_out, int out_size, void* d_ws, size_t ws_size,
                              hipStream_t stream) {
  const float* X = (const float*)d_in[0];
  const float* W = (const float*)d_in[1];
  const float* b = (const float*)d_in[2];
  const float* lam = (const float*)d_in[3];
  float* out = (float*)d_out;

  hipMemsetAsync(out, 0, (size_t)SS * OO * sizeof(float), stream);

  const size_t need = (size_t)2 * SS * DD * sizeof(__bf16);  // 32 MB
  if (ws_size >= need) {
    __bf16* Xb = (__bf16*)d_ws;
    __bf16* Wb = Xb + (size_t)SS * DD;
    const int n4 = SS * DD / 4;
    somfnn_cvt<<<dim3((n4 + 255) / 256), dim3(256), 0, stream>>>(X, Xb, n4);
    somfnn_cvt<<<dim3((n4 + 255) / 256), dim3(256), 0, stream>>>(W, Wb, n4);
    somfnn_gemm<true><<<dim3(512), dim3(256), 0, stream>>>(Xb, Wb, b, lam, out);
  } else {
    somfnn_gemm<false><<<dim3(512), dim3(256), 0, stream>>>(X, W, b, lam, out);
  }
}